// Round 9
// baseline (123.609 us; speedup 1.0000x reference)
//
#include <hip/hip_runtime.h>
#include <hip/hip_bf16.h>

#define N_TOK 16384
#define B_DIM 8
#define C_DIM 256
#define M_ROWS (N_TOK * B_DIM)   // 131072
#define BM 32

typedef __attribute__((ext_vector_type(8))) short short8;
typedef __attribute__((ext_vector_type(4))) float f32x4;

__device__ __forceinline__ unsigned short f2bf(float f) {
    union { float f; unsigned u; } v; v.f = f;
    unsigned r = v.u + 0x7fffu + ((v.u >> 16) & 1u);  // RNE
    return (unsigned short)(r >> 16);
}

__device__ __forceinline__ float bf2f(unsigned short h) {
    union { unsigned u; float f; } v; v.u = ((unsigned)h) << 16;
    return v.f;
}

// packed RNE f32x2 -> bf16x2 (low = a, high = b)
__device__ __forceinline__ unsigned cvt_pk(float a, float b) {
    unsigned r;
    asm("v_cvt_pk_bf16_f32 %0, %1, %2" : "=v"(r) : "v"(a), "v"(b));
    return r;
}

// Kernel A: m -> d_out tail; W fp32 -> bf16 in MFMA-fragment order.
// Wf[((ctile*8 + k8)*64 + lane)*8 + r] = bf16(W[ctile*16 + (lane&15)][k8*32 + (lane>>4)*8 + r])
__global__ __launch_bounds__(256)
void prep_kernel(const int* __restrict__ mask, const int* __restrict__ fg,
                 const float* __restrict__ W, unsigned short* __restrict__ Wf,
                 float* __restrict__ m_out) {
    int i = blockIdx.x * 256 + threadIdx.x;
    if (i < C_DIM * C_DIM) {
        int d = i >> 8;            // W row = output col
        int c = i & 255;           // k
        int ctile = d >> 4;
        int k8    = c >> 5;
        int lane  = ((c >> 3) & 3) * 16 + (d & 15);
        int r     = c & 7;
        Wf[((ctile * 8 + k8) * 64 + lane) * 8 + r] = f2bf(W[i]);
    }
    if (i < M_ROWS) {
        int b = i & (B_DIM - 1);
        int n = i >> 3;
        m_out[i] = (fg[i] != 0) ? (1.0f - (float)mask[b * N_TOK + n]) : 0.0f;
    }
}

// Kernel B: 32-row tile per block (4096 blocks); bf16 x in 16 KB LDS
// (XOR-swizzled); W fragments coalesced from L2 with 1-deep prefetch;
// fused relu+select epilogue reading x back from LDS.
// launch_bounds(256,8): 8 blocks/CU resident -> ~8 concurrent stage phases/CU
// (round-8 analysis: read-MLP was capped by 2.8 resident blocks at bound 4).
__global__ __launch_bounds__(256, 8)
void mlp_kernel(const float* __restrict__ x, const unsigned short* __restrict__ Wf,
                const float* __restrict__ bias, const float* __restrict__ m,
                float* __restrict__ out) {
    __shared__ unsigned short lds_x[BM * C_DIM];  // 16 KB bf16

    const int t    = threadIdx.x;
    const int row0 = blockIdx.x * BM;

    // ---- Stage x tile (32 x 256 fp32 -> bf16 LDS), coalesced 32B/lane ----
    #pragma unroll
    for (int j = 0; j < 4; ++j) {
        int ci  = j * 256 + t;
        int row = ci >> 5;            // 0..31
        int cc  = (ci & 31) * 8;      // 0..248
        const float4* p = (const float4*)(x + (size_t)(row0 + row) * C_DIM + cc);
        float4 a0 = p[0];
        float4 a1 = p[1];
        int4 pk;
        pk.x = (int)cvt_pk(a0.x, a0.y);
        pk.y = (int)cvt_pk(a0.z, a0.w);
        pk.z = (int)cvt_pk(a1.x, a1.y);
        pk.w = (int)cvt_pk(a1.z, a1.w);
        int byte = (row * 512 + cc * 2) ^ ((row & 7) << 4);
        *(int4*)((char*)lds_x + byte) = pk;
    }
    __syncthreads();

    // ---- MFMA: 4 waves x 64 cols, 2(row) x 4(col) 16x16 tiles each ----
    const int lane = t & 63;
    const int wid  = t >> 6;
    const int col0 = wid * 64;
    const int lr   = lane & 15;
    const int kb   = (lane >> 4) * 8;
    const int rsub = (lane >> 4) * 4;   // C/D: row = (lane>>4)*4 + reg

    f32x4 acc[2][4];
    #pragma unroll
    for (int i = 0; i < 2; ++i)
        #pragma unroll
        for (int j = 0; j < 4; ++j) acc[i][j] = (f32x4){0.f, 0.f, 0.f, 0.f};

    // Wave's fragment base: ctile = wid*4 + ct
    const short8* wfb = (const short8*)Wf + (size_t)wid * 4 * 8 * 64 + lane;

    short8 wcur[4], wnxt[4];
    #pragma unroll
    for (int ct = 0; ct < 4; ++ct)
        wcur[ct] = wfb[(ct * 8) * 64];            // k8 = 0, 1 KB coalesced/wave

    #pragma unroll
    for (int k8 = 0; k8 < 8; ++k8) {
        if (k8 < 7) {                              // 1-deep W prefetch from L2
            #pragma unroll
            for (int ct = 0; ct < 4; ++ct)
                wnxt[ct] = wfb[(ct * 8 + k8 + 1) * 64];
        }
        short8 af[2];
        #pragma unroll
        for (int rt = 0; rt < 2; ++rt) {
            int row  = rt * 16 + lr;
            int byte = (row * 512 + (k8 * 32 + kb) * 2) ^ ((row & 7) << 4);
            af[rt] = *(const short8*)((const char*)lds_x + byte);
        }
        #pragma unroll
        for (int rt = 0; rt < 2; ++rt)
            #pragma unroll
            for (int ct = 0; ct < 4; ++ct)
                acc[rt][ct] = __builtin_amdgcn_mfma_f32_16x16x32_bf16(
                    af[rt], wcur[ct], acc[rt][ct], 0, 0, 0);
        #pragma unroll
        for (int ct = 0; ct < 4; ++ct) wcur[ct] = wnxt[ct];
    }

    // ---- Epilogue: relu(acc+b), select vs x (bf16 from LDS), store ----
    float bv[4];
    #pragma unroll
    for (int ct = 0; ct < 4; ++ct) bv[ct] = bias[col0 + ct * 16 + lr];

    #pragma unroll
    for (int rt = 0; rt < 2; ++rt) {
        float4 mreg = *(const float4*)(m + row0 + rt * 16 + rsub);
        #pragma unroll
        for (int r = 0; r < 4; ++r) {
            int lrow = rt * 16 + rsub + r;
            float mv = (r == 0) ? mreg.x : (r == 1) ? mreg.y
                     : (r == 2) ? mreg.z : mreg.w;
            size_t grow = (size_t)row0 + lrow;
            #pragma unroll
            for (int ct = 0; ct < 4; ++ct) {
                int col = col0 + ct * 16 + lr;
                float y = fmaxf(acc[rt][ct][r] + bv[ct], 0.0f);
                int bo = (lrow * 512 + col * 2) ^ ((lrow & 7) << 4);
                float xv = bf2f(*(const unsigned short*)((const char*)lds_x + bo));
                out[grow * C_DIM + col] = (mv != 0.0f) ? y : xv;
            }
        }
    }
}

extern "C" void kernel_launch(void* const* d_in, const int* in_sizes, int n_in,
                              void* d_out, int out_size, void* d_ws, size_t ws_size,
                              hipStream_t stream) {
    const float* x    = (const float*)d_in[0];
    const int*   mask = (const int*)d_in[1];
    const int*   fg   = (const int*)d_in[2];
    const float* W    = (const float*)d_in[3];
    const float* b    = (const float*)d_in[4];

    float* out   = (float*)d_out;
    float* m_out = out + (size_t)M_ROWS * C_DIM;      // output 1: m (N,B)
    unsigned short* Wf = (unsigned short*)d_ws;       // 128 KB fragment-order W

    prep_kernel<<<M_ROWS / 256, 256, 0, stream>>>(mask, fg, W, Wf, m_out);
    mlp_kernel<<<M_ROWS / BM, 256, 0, stream>>>(x, Wf, b, m_out, out);
}

// Round 12
// 69.956 us; speedup vs baseline: 1.7670x; 1.7670x over previous
//
#include <hip/hip_runtime.h>
#include <hip/hip_bf16.h>

#define N_TOK 16384
#define B_DIM 8
#define C_DIM 256
#define M_ROWS (N_TOK * B_DIM)   // 131072

typedef __attribute__((ext_vector_type(8))) short short8;
typedef __attribute__((ext_vector_type(4))) float f32x4;

__device__ __forceinline__ unsigned short f2bf(float f) {
    union { float f; unsigned u; } v; v.f = f;
    unsigned r = v.u + 0x7fffu + ((v.u >> 16) & 1u);  // RNE
    return (unsigned short)(r >> 16);
}

__device__ __forceinline__ float bf2f(unsigned short h) {
    union { unsigned u; float f; } v; v.u = ((unsigned)h) << 16;
    return v.f;
}

// packed RNE f32x2 -> bf16x2 (low = a, high = b)
__device__ __forceinline__ unsigned cvt_pk(float a, float b) {
    unsigned r;
    asm("v_cvt_pk_bf16_f32 %0, %1, %2" : "=v"(r) : "v"(a), "v"(b));
    return r;
}

// Kernel A: m -> d_out tail; W fp32 -> bf16 in MFMA-fragment order.
// Wf[((ctile*8 + k8)*64 + lane)*8 + r] = bf16(W[ctile*16 + (lane&15)][k8*32 + (lane>>4)*8 + r])
__global__ __launch_bounds__(256)
void prep_kernel(const int* __restrict__ mask, const int* __restrict__ fg,
                 const float* __restrict__ W, unsigned short* __restrict__ Wf,
                 float* __restrict__ m_out) {
    int i = blockIdx.x * 256 + threadIdx.x;
    if (i < C_DIM * C_DIM) {
        int d = i >> 8;            // W row = output col
        int c = i & 255;           // k
        int ctile = d >> 4;
        int k8    = c >> 5;
        int lane  = ((c >> 3) & 3) * 16 + (d & 15);
        int r     = c & 7;
        Wf[((ctile * 8 + k8) * 64 + lane) * 8 + r] = f2bf(W[i]);
    }
    if (i < M_ROWS) {
        int b = i & (B_DIM - 1);
        int n = i >> 3;
        m_out[i] = (fg[i] != 0) ? (1.0f - (float)mask[b * N_TOK + n]) : 0.0f;
    }
}

// Kernel B: 2-tile async pipeline, VMEM-free k-loop.
// Block = 64 rows x 128 cols (half = bx&1). 4 waves x 32 cols; W resident in
// regs (64 VGPR). Tile1's loads stay in flight across a RAW s_barrier (no
// vmcnt drain) and land under tile0's compute+epilogue.
__global__ __launch_bounds__(256)
void mlp_kernel(const float* __restrict__ x, const unsigned short* __restrict__ Wf,
                const float* __restrict__ bias, const float* __restrict__ m,
                float* __restrict__ out) {
    __shared__ unsigned short lds_x[2][32 * C_DIM];  // 2 x 16 KB bf16

    const int t    = threadIdx.x;
    const int lane = t & 63;
    const int wid  = t >> 6;                 // 0..3
    const int half = blockIdx.x & 1;
    const int row0 = (blockIdx.x >> 1) * 64;
    const int col0 = half * 128 + wid * 32;
    const int lr   = lane & 15;
    const int kb   = (lane >> 4) * 8;
    const int rsub = (lane >> 4) * 4;        // C/D: row = (lane>>4)*4 + reg

    // ---- 1. W resident: ctiles {col0/16, col0/16+1} x 8 k-steps ----
    short8 wreg[2][8];
    const int ct0 = half * 8 + wid * 2;
    #pragma unroll
    for (int c2 = 0; c2 < 2; ++c2)
        #pragma unroll
        for (int k8 = 0; k8 < 8; ++k8)
            wreg[c2][k8] = ((const short8*)Wf)[(size_t)((ct0 + c2) * 8 + k8) * 64 + lane];
    #pragma unroll
    for (int c2 = 0; c2 < 2; ++c2)
        #pragma unroll
        for (int k8 = 0; k8 < 8; ++k8)
            asm volatile("" : "+v"(wreg[c2][k8]));   // pin W in regs

    float bv[2];
    bv[0] = bias[col0 + lr];
    bv[1] = bias[col0 + 16 + lr];

    // ---- 2. m for both tiles (issued BEFORE tile1 loads: waits won't collide)
    f32x4 m00 = *(const f32x4*)(m + row0 + rsub);
    f32x4 m01 = *(const f32x4*)(m + row0 + 16 + rsub);
    f32x4 m10 = *(const f32x4*)(m + row0 + 32 + rsub);
    f32x4 m11 = *(const f32x4*)(m + row0 + 48 + rsub);

    // ---- 3. Stage tile0 (rows row0..+31): load -> cvt -> LDS buf0 ----
    #pragma unroll
    for (int j = 0; j < 4; ++j) {
        int ci  = j * 256 + t;
        int row = ci >> 5;                   // 0..31
        int cc  = (ci & 31) * 8;             // 0..248
        const f32x4* p = (const f32x4*)(x + (size_t)(row0 + row) * C_DIM + cc);
        f32x4 a0 = p[0];
        f32x4 a1 = p[1];
        int4 pk;
        pk.x = (int)cvt_pk(a0.x, a0.y);
        pk.y = (int)cvt_pk(a0.z, a0.w);
        pk.z = (int)cvt_pk(a1.x, a1.y);
        pk.w = (int)cvt_pk(a1.z, a1.w);
        int byte = (row * 512 + cc * 2) ^ ((row & 7) << 4);
        *(int4*)((char*)&lds_x[0][0] + byte) = pk;
    }

    // ---- 4. Issue tile1 loads (rows row0+32..+63) into held regs ----
    const int r_  = t >> 5;                  // 0..7
    const int cc_ = (t & 31) * 8;            // 0..248
    const float* xb1 = x + (size_t)(row0 + 32) * C_DIM;
    f32x4 g0 = *(const f32x4*)(xb1 + (size_t)(r_     ) * C_DIM + cc_);
    f32x4 g1 = *(const f32x4*)(xb1 + (size_t)(r_     ) * C_DIM + cc_ + 4);
    f32x4 g2 = *(const f32x4*)(xb1 + (size_t)(r_ +  8) * C_DIM + cc_);
    f32x4 g3 = *(const f32x4*)(xb1 + (size_t)(r_ +  8) * C_DIM + cc_ + 4);
    f32x4 g4 = *(const f32x4*)(xb1 + (size_t)(r_ + 16) * C_DIM + cc_);
    f32x4 g5 = *(const f32x4*)(xb1 + (size_t)(r_ + 16) * C_DIM + cc_ + 4);
    f32x4 g6 = *(const f32x4*)(xb1 + (size_t)(r_ + 24) * C_DIM + cc_);
    f32x4 g7 = *(const f32x4*)(xb1 + (size_t)(r_ + 24) * C_DIM + cc_ + 4);
    __builtin_amdgcn_sched_barrier(0);       // pin issue point (no wait forced)

    // ---- 5. barrier WITHOUT vmcnt drain: tile1 loads stay in flight ----
    asm volatile("s_waitcnt lgkmcnt(0)" ::: "memory");
    __builtin_amdgcn_s_barrier();
    asm volatile("" ::: "memory");

    // ---- per-tile compute (pure LDS+MFMA) + epilogue (stores only) ----
    auto do_tile = [&](const char* Lc, int trow0, f32x4 mA, f32x4 mB) {
        f32x4 acc[2][2];
        #pragma unroll
        for (int i = 0; i < 2; ++i)
            #pragma unroll
            for (int j = 0; j < 2; ++j) acc[i][j] = (f32x4){0.f, 0.f, 0.f, 0.f};

        #pragma unroll
        for (int k8 = 0; k8 < 8; ++k8) {
            short8 af[2];
            #pragma unroll
            for (int rt = 0; rt < 2; ++rt) {
                int row  = rt * 16 + lr;
                int byte = (row * 512 + (k8 * 32 + kb) * 2) ^ ((row & 7) << 4);
                af[rt] = *(const short8*)(Lc + byte);
            }
            #pragma unroll
            for (int rt = 0; rt < 2; ++rt)
                #pragma unroll
                for (int c2 = 0; c2 < 2; ++c2)
                    acc[rt][c2] = __builtin_amdgcn_mfma_f32_16x16x32_bf16(
                        af[rt], wreg[c2][k8], acc[rt][c2], 0, 0, 0);
        }

        #pragma unroll
        for (int rt = 0; rt < 2; ++rt) {
            f32x4 mr = rt ? mB : mA;
            #pragma unroll
            for (int r = 0; r < 4; ++r) {
                int lrow = rt * 16 + rsub + r;
                float mv = mr[r];
                size_t grow = (size_t)trow0 + lrow;
                #pragma unroll
                for (int c2 = 0; c2 < 2; ++c2) {
                    int col = col0 + c2 * 16 + lr;
                    float y = fmaxf(acc[rt][c2][r] + bv[c2], 0.0f);
                    int bo = (lrow * 512 + col * 2) ^ ((lrow & 7) << 4);
                    float xv = bf2f(*(const unsigned short*)(Lc + bo));
                    out[grow * C_DIM + col] = (mv != 0.0f) ? y : xv;
                }
            }
        }
    };

    // ---- 6. tile0 compute+epilogue (tile1 loads in flight under it) ----
    do_tile((const char*)&lds_x[0][0], row0, m00, m01);

    // ---- 7. cvt tile1 -> LDS buf1 (wait leaves only stores outstanding) ----
    {
        int sz = (r_ & 7) << 4;              // rows r_, r_+8, r_+16, r_+24: same &7
        int4 pk;
        pk.x = (int)cvt_pk(g0.x, g0.y); pk.y = (int)cvt_pk(g0.z, g0.w);
        pk.z = (int)cvt_pk(g1.x, g1.y); pk.w = (int)cvt_pk(g1.z, g1.w);
        *(int4*)((char*)&lds_x[1][0] + (((r_     ) * 512 + cc_ * 2) ^ sz)) = pk;
        pk.x = (int)cvt_pk(g2.x, g2.y); pk.y = (int)cvt_pk(g2.z, g2.w);
        pk.z = (int)cvt_pk(g3.x, g3.y); pk.w = (int)cvt_pk(g3.z, g3.w);
        *(int4*)((char*)&lds_x[1][0] + (((r_ +  8) * 512 + cc_ * 2) ^ sz)) = pk;
        pk.x = (int)cvt_pk(g4.x, g4.y); pk.y = (int)cvt_pk(g4.z, g4.w);
        pk.z = (int)cvt_pk(g5.x, g5.y); pk.w = (int)cvt_pk(g5.z, g5.w);
        *(int4*)((char*)&lds_x[1][0] + (((r_ + 16) * 512 + cc_ * 2) ^ sz)) = pk;
        pk.x = (int)cvt_pk(g6.x, g6.y); pk.y = (int)cvt_pk(g6.z, g6.w);
        pk.z = (int)cvt_pk(g7.x, g7.y); pk.w = (int)cvt_pk(g7.z, g7.w);
        *(int4*)((char*)&lds_x[1][0] + (((r_ + 24) * 512 + cc_ * 2) ^ sz)) = pk;
    }
    asm volatile("s_waitcnt lgkmcnt(0)" ::: "memory");
    __builtin_amdgcn_s_barrier();
    asm volatile("" ::: "memory");

    // ---- 8. tile1 compute+epilogue ----
    do_tile((const char*)&lds_x[1][0], row0 + 32, m10, m11);
}

extern "C" void kernel_launch(void* const* d_in, const int* in_sizes, int n_in,
                              void* d_out, int out_size, void* d_ws, size_t ws_size,
                              hipStream_t stream) {
    const float* x    = (const float*)d_in[0];
    const int*   mask = (const int*)d_in[1];
    const int*   fg   = (const int*)d_in[2];
    const float* W    = (const float*)d_in[3];
    const float* b    = (const float*)d_in[4];

    float* out   = (float*)d_out;
    float* m_out = out + (size_t)M_ROWS * C_DIM;      // output 1: m (N,B)
    unsigned short* Wf = (unsigned short*)d_ws;       // 128 KB fragment-order W

    prep_kernel<<<M_ROWS / 256, 256, 0, stream>>>(mask, fg, W, Wf, m_out);
    mlp_kernel<<<(M_ROWS / 64) * 2, 256, 0, stream>>>(x, Wf, b, m_out, out);
}